// Round 1
// baseline (884.531 us; speedup 1.0000x reference)
//
#include <hip/hip_runtime.h>

// SparseConv2D on MI355X (gfx950).
// Collapses reference gather->conv(SAME)->crop->scatter into a valid 3x3 conv:
//   out[n,r,c,co] = active[n,r/14,c/14] * (bias[co] +
//       sum_{dr,dc,ci} x[n,r+dr,c+dc,ci] * K[dr,dc,ci,co]),  r,c in [0,504)
// One workgroup per 14x14x32 output tile; input tile 16x16x32 staged in LDS
// transposed to [ci][r][c] so row reads are ds_read_b128 broadcasts.

#define BS   16
#define ST   14
#define NBH  36
#define NBW  36
#define NN   8
#define HH   506
#define WW   506
#define CIN  32
#define COUT 32
#define OH   504
#define OW   504

// ci stride in floats: 16*16 + 4 pad -> 1040 B (16B-multiple, b128-aligned),
// and breaks the power-of-2 bank stride on the transpose writes.
#define XS_CI_STRIDE 260

__global__ __launch_bounds__(448) void sparse_conv_kernel(
    const float* __restrict__ x, const float* __restrict__ mask,
    const float* __restrict__ kern, const float* __restrict__ bias,
    float* __restrict__ out)
{
    __shared__ float xs[CIN * XS_CI_STRIDE];  // 33280 B
    __shared__ float sred[8];
    __shared__ float sflag;

    const int bw = blockIdx.x, bh = blockIdx.y, n = blockIdx.z;
    const int t  = threadIdx.x;
    const int r0 = bh * ST, c0 = bw * ST;

    // ---- mask block max -> active flag (branchless gating) ----
    float m = 0.0f;
    if (t < 256) {
        const int i = t >> 4, j = t & 15;
        m = mask[(size_t)(n * HH + r0 + i) * WW + (c0 + j)];
    }
    #pragma unroll
    for (int off = 32; off > 0; off >>= 1)
        m = fmaxf(m, __shfl_down(m, off, 64));
    if ((t & 63) == 0) sred[t >> 6] = m;   // waves 0..6 write; only 0..3 matter
    __syncthreads();
    if (t == 0) {
        const float mm = fmaxf(fmaxf(sred[0], sred[1]), fmaxf(sred[2], sred[3]));
        sflag = (mm > 0.5f) ? 1.0f : 0.0f;
    }

    // ---- stage input tile 16x16x32 (2048 float4), transpose to [ci][r][c] ----
    for (int q = t; q < 2048; q += 448) {
        const int r = q >> 7;          // 128 float4 per input row
        const int o = q & 127;
        const int c = o >> 3;          // column 0..15
        const int ci4 = o & 7;         // channel group (4 ch per float4)
        const float4 v = *(const float4*)(
            x + ((size_t)(n * HH + r0 + r) * WW + (c0 + c)) * CIN + ci4 * 4);
        float* p = &xs[(ci4 * 4) * XS_CI_STRIDE + r * 16 + c];
        p[0]                = v.x;
        p[XS_CI_STRIDE]     = v.y;
        p[2 * XS_CI_STRIDE] = v.z;
        p[3 * XS_CI_STRIDE] = v.w;
    }
    __syncthreads();

    const float flag = sflag;
    const int co = t & 31;
    const int g  = t >> 5;             // 0..13 : output row within tile

    float acc[14];
    #pragma unroll
    for (int i = 0; i < 14; ++i) acc[i] = 0.0f;

    for (int dr = 0; dr < 3; ++dr) {
        const int r = g + dr;
        for (int ci = 0; ci < 32; ++ci) {
            // 16-float input row: 4x ds_read_b128, broadcast across the group
            const float4* xr4 = (const float4*)&xs[ci * XS_CI_STRIDE + r * 16];
            const float4 v0 = xr4[0], v1 = xr4[1], v2 = xr4[2], v3 = xr4[3];
            float xv[16];
            xv[0]=v0.x; xv[1]=v0.y; xv[2]=v0.z; xv[3]=v0.w;
            xv[4]=v1.x; xv[5]=v1.y; xv[6]=v1.z; xv[7]=v1.w;
            xv[8]=v2.x; xv[9]=v2.y; xv[10]=v2.z; xv[11]=v2.w;
            xv[12]=v3.x; xv[13]=v3.y; xv[14]=v3.z; xv[15]=v3.w;
            #pragma unroll
            for (int dc = 0; dc < 3; ++dc) {
                // all 64 lanes of a wave read the same 128B line -> L1 hit
                const float k = kern[((dr * 3 + dc) * 32 + ci) * 32 + co];
                #pragma unroll
                for (int oj = 0; oj < 14; ++oj)
                    acc[oj] = fmaf(xv[oj + dc], k, acc[oj]);
            }
        }
    }

    const float bv = bias[co];
    const size_t obase = ((size_t)(n * OH + r0 + g) * OW + c0) * COUT + co;
    #pragma unroll
    for (int oj = 0; oj < 14; ++oj)
        out[obase + (size_t)oj * COUT] = (acc[oj] + bv) * flag;
}

extern "C" void kernel_launch(void* const* d_in, const int* in_sizes, int n_in,
                              void* d_out, int out_size, void* d_ws, size_t ws_size,
                              hipStream_t stream) {
    const float* x    = (const float*)d_in[0];
    const float* mask = (const float*)d_in[1];
    const float* kern = (const float*)d_in[2];
    const float* bias = (const float*)d_in[3];
    float* out        = (float*)d_out;

    dim3 grid(NBW, NBH, NN);   // 36 x 36 x 8 = 10368 tiles
    sparse_conv_kernel<<<grid, 448, 0, stream>>>(x, mask, kern, bias, out);
}